// Round 11
// baseline (301.435 us; speedup 1.0000x reference)
//
#include <hip/hip_runtime.h>
#include <hip/hip_bf16.h>
#include <hip/hip_fp16.h>

#define N_NODES 100000
#define N_EDGES 3200000
#define F_IN    128
#define F_H     64

#define NBUCK 256
#define NPB   391            // ceil(N_NODES / NBUCK); last bucket short
#define SRC_BITS 17          // N_NODES < 2^17; pack = (dstLocal<<17)|src
#define BCAP  16384          // fixed per-bucket capacity (mean 12.5K, 35 sigma)
#define CAPL  72             // per-node LDS row capacity (mean 32, +7 sigma)

// ---------------------------------------------------------------------------
// Init: bucket cursors to fixed bases; wc2 = W2^T Wc; c0 = Wc.b2 + bc
// ---------------------------------------------------------------------------
__global__ __launch_bounds__(256) void k_init(const float* __restrict__ W2,
                                              const float* __restrict__ Wc,
                                              const float* __restrict__ b2,
                                              const float* __restrict__ bc,
                                              float* __restrict__ wc2,
                                              float* __restrict__ c0,
                                              int* __restrict__ bcur) {
    int t = threadIdx.x;
    bcur[t] = t * BCAP;
    if (t < 64) {
        float s = 0.0f;
#pragma unroll 8
        for (int f = 0; f < F_H; f++) s += Wc[f] * W2[f * F_H + t];
        wc2[t] = s;
        float p = Wc[t] * b2[t];
#pragma unroll
        for (int off = 32; off > 0; off >>= 1) p += __shfl_xor(p, off, 64);
        if (t == 0) c0[0] = p + bc[0];
    }
}

// ---------------------------------------------------------------------------
// Pass A: partition edges into NBUCK fixed-capacity dst-range buckets; emit
// packed (dstLocal<<17)|src words (LDS-staged, coalesced out)
// ---------------------------------------------------------------------------
#define PA_T   256
#define PA_C   4096
#define PA_PER (PA_C / PA_T)   // 16
__global__ __launch_bounds__(PA_T) void k_partA(const int* __restrict__ src,
                                                const int* __restrict__ dst,
                                                int* __restrict__ bucket_cursor,
                                                int* __restrict__ packT) {
    __shared__ int lcount[NBUCK];
    __shared__ int lstart[NBUCK];
    __shared__ int loffs[NBUCK];
    __shared__ int lbase[NBUCK];
    __shared__ int s_pack[PA_C];
    __shared__ unsigned char s_bkt[PA_C];
    __shared__ int ltot;
    int t = threadIdx.x;
    long long e0 = (long long)blockIdx.x * PA_C;
    if (t < NBUCK) lcount[t] = 0;
    __syncthreads();
    int ep[PA_PER];
    short eb[PA_PER];
#pragma unroll
    for (int i = 0; i < PA_PER; i++) {
        long long e = e0 + i * PA_T + t;
        if (e < N_EDGES) {
            int es = src[e], ed = dst[e];
            int b = ed / NPB;
            eb[i] = (short)b;
            ep[i] = ((ed - b * NPB) << SRC_BITS) | es;
            atomicAdd(&lcount[b], 1);
        } else eb[i] = -1;
    }
    __syncthreads();
    // exclusive scan of lcount (256) by wave 0: 4 serial/lane + shfl scan
    if (t < 64) {
        int base = t * 4;
        int c0 = lcount[base], c1 = lcount[base + 1], c2 = lcount[base + 2], c3 = lcount[base + 3];
        int ssum = c0 + c1 + c2 + c3;
        int sc = ssum;
#pragma unroll
        for (int off = 1; off < 64; off <<= 1) {
            int v = __shfl_up(sc, off, 64);
            if (t >= off) sc += v;
        }
        int ex = sc - ssum;
        lstart[base]     = ex;
        lstart[base + 1] = ex + c0;
        lstart[base + 2] = ex + c0 + c1;
        lstart[base + 3] = ex + c0 + c1 + c2;
        if (t == 63) ltot = sc;
    }
    __syncthreads();
    if (t < NBUCK) {
        loffs[t] = lstart[t];
        int c = lcount[t];
        lbase[t] = c ? atomicAdd(&bucket_cursor[t], c) : 0;
    }
    __syncthreads();
#pragma unroll
    for (int i = 0; i < PA_PER; i++) {
        if (eb[i] >= 0) {
            int idx = atomicAdd(&loffs[eb[i]], 1);
            s_pack[idx] = ep[i];
            s_bkt[idx] = (unsigned char)eb[i];
        }
    }
    __syncthreads();
    int tot = ltot;
    for (int i = t; i < tot; i += PA_T) {
        int b = s_bkt[i];
        int addr = lbase[b] + (i - lstart[b]);
        packT[addr] = s_pack[i];
    }
}

// ---------------------------------------------------------------------------
// Pass B v3: ONE atomic pass. Scatter edges into LDS-padded per-node rows
// (113 KB), scan counts -> rowinfo=(deg<<22)|start, then wave-per-node
// COALESCED compact write to srcs.
// ---------------------------------------------------------------------------
#define PB_T   1024
__global__ __launch_bounds__(PB_T) void k_partB(const int* __restrict__ bcur,
                                                const int* __restrict__ packT,
                                                int* __restrict__ rowinfo,
                                                int* __restrict__ srcs) {
    __shared__ int cnt[NPB];
    __shared__ int stt[NPB];
    __shared__ int srow[NPB * CAPL];    // 112.6 KB
    int b = blockIdx.x;
    int node0 = b * NPB;
    int nloc = min(NPB, N_NODES - node0);
    int beg = b * BCAP;
    int len = bcur[b] - beg;
    if (len > BCAP) len = BCAP;          // 35-sigma guard
    int t = threadIdx.x;
    const int SMASK = (1 << SRC_BITS) - 1;

    for (int i = t; i < NPB; i += PB_T) cnt[i] = 0;
    __syncthreads();
    for (int i = t; i < len; i += PB_T) {
        int pk = packT[beg + i];
        int dl = pk >> SRC_BITS;
        int pos = atomicAdd(&cnt[dl], 1);
        if (pos < CAPL)                  // +7-sigma guard
            srow[dl * CAPL + pos] = pk & SMASK;
    }
    __syncthreads();
    if (t < 64) {   // exclusive scan of 391 counters: 7/lane + shfl
        int base = t * 7;
        int c[7]; int ssum = 0;
#pragma unroll
        for (int j = 0; j < 7; j++) {
            int idx = base + j;
            c[j] = (idx < NPB) ? min(cnt[idx], CAPL) : 0;
            ssum += c[j];
        }
        int sc = ssum;
#pragma unroll
        for (int off = 1; off < 64; off <<= 1) {
            int v = __shfl_up(sc, off, 64);
            if (t >= off) sc += v;
        }
        int ex = sc - ssum;
#pragma unroll
        for (int j = 0; j < 7; j++) {
            int idx = base + j;
            if (idx < NPB) stt[idx] = ex;
            ex += c[j];
        }
    }
    __syncthreads();
    for (int i = t; i < nloc; i += PB_T) {
        int d = min(cnt[i], CAPL);
        rowinfo[node0 + i] = (d << 22) | (beg + stt[i]);
    }
    // compact coalesced copy: wave per node, stride 16 waves
    int lane = t & 63, wv = t >> 6;
    for (int i = wv; i < nloc; i += 16) {
        int d = min(cnt[i], CAPL);
        int o = beg + stt[i];
        for (int p = lane; p < d; p += 64)
            srcs[o + p] = srow[i * CAPL + p];
    }
}

// ---------------------------------------------------------------------------
// Layer-1 GEMM: hs16 = fp16( (x @ W1^T) * dinv ). KT=32 tiling + 1-deep
// register prefetch. Same FMA order -> bit-identical fp32 math.
// ---------------------------------------------------------------------------
#define GT   256
#define NTB  128     // nodes per block
#define KT2  32      // k-tile (4 passes for F_IN=128)
#define WS   68      // wT stride (floats)

__global__ __launch_bounds__(GT, 4) void k_gemm1(const float* __restrict__ x,
                                                 const float* __restrict__ W1,
                                                 const int* __restrict__ rowinfo,
                                                 __half* __restrict__ hs) {
    __shared__ float wT[KT2 * WS];      // 8.7 KB
    __shared__ float xT[KT2 * NTB];     // 16 KB
    int t = threadIdx.x;
    int node0 = blockIdx.x * NTB;
    int lane = t & 63, wv = t >> 6;
    int fi = lane & 15, ni = lane >> 4;
    int n0 = wv * 32 + ni * 8;
    // staging roles
    int fW = t & 63, kqW = t >> 6;       // wT: 8 k values (2 float4)
    int nX = t & 127, halfX = t >> 7;    // xT: 16 k values (4 float4)
    int nodeX = node0 + nX;
    bool xok = (nodeX < N_NODES);

    float4 wv_[2], xv_[4];
    {   // prologue: load pass-0 staging into registers
        const float4* wp = (const float4*)&W1[(size_t)fW * F_IN + kqW * 8];
        wv_[0] = wp[0]; wv_[1] = wp[1];
        if (xok) {
            const float4* xp = (const float4*)&x[(size_t)nodeX * F_IN + halfX * 16];
#pragma unroll
            for (int j = 0; j < 4; j++) xv_[j] = xp[j];
        } else {
#pragma unroll
            for (int j = 0; j < 4; j++) xv_[j] = make_float4(0.f, 0.f, 0.f, 0.f);
        }
    }

    float acc[4][8];
#pragma unroll
    for (int r = 0; r < 4; r++)
#pragma unroll
        for (int c = 0; c < 8; c++) acc[r][c] = 0.0f;

    for (int p = 0; p < 4; p++) {
        if (p) __syncthreads();          // prev compute done before LDS overwrite
        {   // write staged registers -> LDS
#pragma unroll
            for (int j = 0; j < 2; j++) {
                float4 v = wv_[j];
                int kl = kqW * 8 + 4 * j;
                wT[(kl + 0) * WS + fW] = v.x;
                wT[(kl + 1) * WS + fW] = v.y;
                wT[(kl + 2) * WS + fW] = v.z;
                wT[(kl + 3) * WS + fW] = v.w;
            }
#pragma unroll
            for (int j = 0; j < 4; j++) {
                float4 v = xv_[j];
                int kl = (halfX * 4 + j) * 4;
                xT[(kl + 0) * NTB + nX] = v.x;
                xT[(kl + 1) * NTB + nX] = v.y;
                xT[(kl + 2) * NTB + nX] = v.z;
                xT[(kl + 3) * NTB + nX] = v.w;
            }
        }
        __syncthreads();
        if (p < 3) {                     // prefetch next pass during compute
            int k0n = (p + 1) * KT2;
            const float4* wp = (const float4*)&W1[(size_t)fW * F_IN + k0n + kqW * 8];
            wv_[0] = wp[0]; wv_[1] = wp[1];
            if (xok) {
                const float4* xp = (const float4*)&x[(size_t)nodeX * F_IN + k0n + halfX * 16];
#pragma unroll
                for (int j = 0; j < 4; j++) xv_[j] = xp[j];
            }
        }
#pragma unroll 8
        for (int k = 0; k < KT2; k++) {
            float4 wf = *(const float4*)&wT[k * WS + fi * 4];
            float4 xa = *(const float4*)&xT[k * NTB + n0];
            float4 xb = *(const float4*)&xT[k * NTB + n0 + 4];
            float wr[4] = {wf.x, wf.y, wf.z, wf.w};
            float xv[8] = {xa.x, xa.y, xa.z, xa.w, xb.x, xb.y, xb.z, xb.w};
#pragma unroll
            for (int r = 0; r < 4; r++)
#pragma unroll
                for (int c = 0; c < 8; c++) acc[r][c] += wr[r] * xv[c];
        }
    }
#pragma unroll
    for (int c = 0; c < 8; c++) {
        int node = node0 + n0 + c;
        if (node < N_NODES) {
            float dv = rsqrtf((float)((rowinfo[node] >> 22) + 1));
            __half2 h0 = __floats2half2_rn(acc[0][c] * dv, acc[1][c] * dv);
            __half2 h1 = __floats2half2_rn(acc[2][c] * dv, acc[3][c] * dv);
            __half2* hp = (__half2*)&hs[(size_t)node * F_H + fi * 4];
            hp[0] = h0; hp[1] = h1;
        }
    }
}

// ---------------------------------------------------------------------------
// Aggregate L1 + relu + wc2 projection. Round-0 proven body; split 4-way
// THIS ROUND ONLY (quarters ~27 us) so the rocprof top-5 window drops below
// the hidden kernels and reveals the slowest of partA/partB/gemm with
// counters. Known cost ~+13 us vs single dispatch; reverts next round.
// ---------------------------------------------------------------------------
__global__ void k_agg1q(const int* __restrict__ rowinfo, const int* __restrict__ srcs,
                        const __half* __restrict__ hs,
                        const float* __restrict__ b1, const float* __restrict__ wc2,
                        float* __restrict__ q, int node_base) {
    unsigned tid = blockIdx.x * blockDim.x + threadIdx.x;
    unsigned node = node_base + (tid >> 6);
    int lane = tid & 63;
    if (node >= N_NODES) return;
    int up = lane >> 5;            // 0 = even edges, 1 = odd edges
    int fp = lane & 31;            // feature pair: features 2fp, 2fp+1
    const __half2* hs2 = (const __half2*)hs;

    int ri = rowinfo[node];
    int beg = ri & 0x3FFFFF;
    int deg = ri >> 22;
    int end = beg + deg;
    float2 acc = make_float2(0.0f, 0.0f);
    if (up == 0) {                 // self-loop on lower half only
        float2 s = __half22float2(hs2[(size_t)node * 32 + fp]);
        acc.x = s.x; acc.y = s.y;
    }
    int j = beg;
    for (; j + 16 <= end; j += 16) {
        int s[16];
#pragma unroll
        for (int u = 0; u < 16; u++) s[u] = srcs[j + u];
#pragma unroll
        for (int u = 0; u < 8; u++) {
            int sel = up ? s[2 * u + 1] : s[2 * u];
            float2 v = __half22float2(hs2[(size_t)sel * 32 + fp]);
            acc.x += v.x; acc.y += v.y;
        }
    }
    for (; j + 2 <= end; j += 2) {
        int sel = up ? srcs[j + 1] : srcs[j];
        float2 v = __half22float2(hs2[(size_t)sel * 32 + fp]);
        acc.x += v.x; acc.y += v.y;
    }
    if (j < end && up == 0) {      // odd leftover edge: lower half only
        float2 v = __half22float2(hs2[(size_t)srcs[j] * 32 + fp]);
        acc.x += v.x; acc.y += v.y;
    }
    // combine halves (both halves then hold the full sum)
    acc.x += __shfl_xor(acc.x, 32, 64);
    acc.y += __shfl_xor(acc.y, 32, 64);
    // epilogue: z = relu(dinv*acc + b1); q = dinv * dot(z, wc2)
    float dv = rsqrtf((float)(deg + 1));
    float2 bb = *(const float2*)&b1[2 * fp];
    float2 ww = *(const float2*)&wc2[2 * fp];
    float z0 = fmaxf(fmaf(dv, acc.x, bb.x), 0.0f);
    float z1 = fmaxf(fmaf(dv, acc.y, bb.y), 0.0f);
    float p = z0 * ww.x + z1 * ww.y;
#pragma unroll
    for (int off = 16; off > 0; off >>= 1)
        p += __shfl_xor(p, off, 64);
    if (lane == 0) q[node] = dv * p;
}

// ---------------------------------------------------------------------------
// Final: out[d] = dinv[d] * (q[d] + sum_{s->d} q[s]) + c0
// 8 lanes per node, coalesced 32B srcs reads per group, 3-step shfl reduce.
// ---------------------------------------------------------------------------
#define KF_T 256
__global__ __launch_bounds__(KF_T) void k_final(const int* __restrict__ rowinfo,
                                                const int* __restrict__ srcs,
                                                const float* __restrict__ q,
                                                const float* __restrict__ c0,
                                                float* __restrict__ out) {
    int t = blockIdx.x * KF_T + threadIdx.x;
    int node = t >> 3;
    int sl = t & 7;
    if (node >= N_NODES) return;
    int ri = rowinfo[node];
    int beg = ri & 0x3FFFFF;
    int deg = ri >> 22;
    float acc = 0.0f;
    for (int j = beg + sl; j < beg + deg; j += 8)
        acc += q[srcs[j]];
    acc += __shfl_xor(acc, 1, 64);
    acc += __shfl_xor(acc, 2, 64);
    acc += __shfl_xor(acc, 4, 64);
    if (sl == 0)
        out[node] = rsqrtf((float)(deg + 1)) * (q[node] + acc) + c0[0];
}

// ---------------------------------------------------------------------------
extern "C" void kernel_launch(void* const* d_in, const int* in_sizes, int n_in,
                              void* d_out, int out_size, void* d_ws, size_t ws_size,
                              hipStream_t stream) {
    const float* x  = (const float*)d_in[0];
    const int*   ei = (const int*)d_in[1];
    const int*   src = ei;
    const int*   dst = ei + N_EDGES;
    const float* W1 = (const float*)d_in[2];
    const float* b1 = (const float*)d_in[3];
    const float* W2 = (const float*)d_in[4];
    const float* b2 = (const float*)d_in[5];
    const float* Wc = (const float*)d_in[6];
    const float* bc = (const float*)d_in[7];
    float* out = (float*)d_out;

    char* w = (char*)d_ws;
    int*    bcur    = (int*)w;    w += NBUCK * 4;
    float*  wc2     = (float*)w;  w += 64 * 4;
    float*  c0      = (float*)w;  w += 4 * 4;
    int*    rowinfo = (int*)w;    w += (size_t)N_NODES * 4;
    float*  q       = (float*)w;  w += (size_t)N_NODES * 4;
    int*    srcs    = (int*)w;    w += (size_t)NBUCK * BCAP * 4;    // 16.8 MB
    // packT dead after k_partB; bufA (hs) written by k_gemm1 afterwards -> alias
    char*   shared_region = w;
    int*    packT   = (int*)shared_region;     // NBUCK*BCAP*4 = 16.8 MB
    __half* bufA    = (__half*)shared_region;  // N_NODES*128 B = 12.8 MB
    w += (size_t)NBUCK * BCAP * 4 + 256;

    const int TB = 256;
    const int NB_PA = (int)(((long long)N_EDGES + PA_C - 1) / PA_C);  // 782
    const int NB_G  = (N_NODES + NTB - 1) / NTB;                      // 782
    const int NQ = 25000;
    const int NB_AG = (NQ * 64) / TB;                                 // 6250
    const int NB_KF = (N_NODES * 8 + KF_T - 1) / KF_T;                // 3125

    k_init <<<1, 256, 0, stream>>>(W2, Wc, b2, bc, wc2, c0, bcur);
    k_partA<<<NB_PA, PA_T, 0, stream>>>(src, dst, bcur, packT);
    k_partB<<<NBUCK, PB_T, 0, stream>>>(bcur, packT, rowinfo, srcs);

    // layer 1: gemm (KT=32 + register prefetch) -> hs fp16 (overwrites packT)
    k_gemm1<<<NB_G, GT, 0, stream>>>(x, W1, rowinfo, bufA);

    // aggregate+relu+project -> q (FOUR quarter dispatches: visibility round)
    k_agg1q<<<NB_AG, TB, 0, stream>>>(rowinfo, srcs, bufA, b1, wc2, q, 0);
    k_agg1q<<<NB_AG, TB, 0, stream>>>(rowinfo, srcs, bufA, b1, wc2, q, NQ);
    k_agg1q<<<NB_AG, TB, 0, stream>>>(rowinfo, srcs, bufA, b1, wc2, q, 2 * NQ);
    k_agg1q<<<NB_AG, TB, 0, stream>>>(rowinfo, srcs, bufA, b1, wc2, q, 3 * NQ);

    // collapsed layer 2 + head: 8-lane-per-node gather over q
    k_final<<<NB_KF, KF_T, 0, stream>>>(rowinfo, srcs, q, c0, out);
}

// Round 12
// 281.970 us; speedup vs baseline: 1.0690x; 1.0690x over previous
//
#include <hip/hip_runtime.h>
#include <hip/hip_bf16.h>
#include <hip/hip_fp16.h>

#define N_NODES 100000
#define N_EDGES 3200000
#define F_IN    128
#define F_H     64

#define NBUCK 256
#define NPB   391            // ceil(N_NODES / NBUCK); last bucket short
#define SRC_BITS 17          // N_NODES < 2^17; pack = (dstLocal<<17)|src
#define BCAP  16384          // fixed per-bucket capacity (mean 12.5K, 35 sigma)

// ---------------------------------------------------------------------------
// Init: bucket cursors to fixed bases; wc2 = W2^T Wc; c0 = Wc.b2 + bc
// ---------------------------------------------------------------------------
__global__ __launch_bounds__(256) void k_init(const float* __restrict__ W2,
                                              const float* __restrict__ Wc,
                                              const float* __restrict__ b2,
                                              const float* __restrict__ bc,
                                              float* __restrict__ wc2,
                                              float* __restrict__ c0,
                                              int* __restrict__ bcur) {
    int t = threadIdx.x;
    bcur[t] = t * BCAP;
    if (t < 64) {
        float s = 0.0f;
#pragma unroll 8
        for (int f = 0; f < F_H; f++) s += Wc[f] * W2[f * F_H + t];
        wc2[t] = s;
        float p = Wc[t] * b2[t];
#pragma unroll
        for (int off = 32; off > 0; off >>= 1) p += __shfl_xor(p, off, 64);
        if (t == 0) c0[0] = p + bc[0];
    }
}

// ---------------------------------------------------------------------------
// Pass A: partition edges into NBUCK fixed-capacity dst-range buckets; emit
// packed (dstLocal<<17)|src words (LDS-staged, coalesced out)
// ---------------------------------------------------------------------------
#define PA_T   256
#define PA_C   4096
#define PA_PER (PA_C / PA_T)   // 16
__global__ __launch_bounds__(PA_T) void k_partA(const int* __restrict__ src,
                                                const int* __restrict__ dst,
                                                int* __restrict__ bucket_cursor,
                                                int* __restrict__ packT) {
    __shared__ int lcount[NBUCK];
    __shared__ int lstart[NBUCK];
    __shared__ int loffs[NBUCK];
    __shared__ int lbase[NBUCK];
    __shared__ int s_pack[PA_C];
    __shared__ unsigned char s_bkt[PA_C];
    __shared__ int ltot;
    int t = threadIdx.x;
    long long e0 = (long long)blockIdx.x * PA_C;
    if (t < NBUCK) lcount[t] = 0;
    __syncthreads();
    int ep[PA_PER];
    short eb[PA_PER];
#pragma unroll
    for (int i = 0; i < PA_PER; i++) {
        long long e = e0 + i * PA_T + t;
        if (e < N_EDGES) {
            int es = src[e], ed = dst[e];
            int b = ed / NPB;
            eb[i] = (short)b;
            ep[i] = ((ed - b * NPB) << SRC_BITS) | es;
            atomicAdd(&lcount[b], 1);
        } else eb[i] = -1;
    }
    __syncthreads();
    // exclusive scan of lcount (256) by wave 0: 4 serial/lane + shfl scan
    if (t < 64) {
        int base = t * 4;
        int c0 = lcount[base], c1 = lcount[base + 1], c2 = lcount[base + 2], c3 = lcount[base + 3];
        int ssum = c0 + c1 + c2 + c3;
        int sc = ssum;
#pragma unroll
        for (int off = 1; off < 64; off <<= 1) {
            int v = __shfl_up(sc, off, 64);
            if (t >= off) sc += v;
        }
        int ex = sc - ssum;
        lstart[base]     = ex;
        lstart[base + 1] = ex + c0;
        lstart[base + 2] = ex + c0 + c1;
        lstart[base + 3] = ex + c0 + c1 + c2;
        if (t == 63) ltot = sc;
    }
    __syncthreads();
    if (t < NBUCK) {
        loffs[t] = lstart[t];
        int c = lcount[t];
        lbase[t] = c ? atomicAdd(&bucket_cursor[t], c) : 0;
    }
    __syncthreads();
#pragma unroll
    for (int i = 0; i < PA_PER; i++) {
        if (eb[i] >= 0) {
            int idx = atomicAdd(&loffs[eb[i]], 1);
            s_pack[idx] = ep[i];
            s_bkt[idx] = (unsigned char)eb[i];
        }
    }
    __syncthreads();
    int tot = ltot;
    for (int i = t; i < tot; i += PA_T) {
        int b = s_bkt[i];
        int addr = lbase[b] + (i - lstart[b]);
        packT[addr] = s_pack[i];
    }
}

// ---------------------------------------------------------------------------
// Pass B: R6-proven full counting sort (measured-best config). Histogram
// pass + scan + LDS s_out scatter + coalesced copy-out. emits rowinfo.
// ---------------------------------------------------------------------------
#define PB_T   1024
#define PB_CAP 16384
__global__ __launch_bounds__(PB_T) void k_partB(const int* __restrict__ bcur,
                                                const int* __restrict__ packT,
                                                int* __restrict__ rowinfo,
                                                int* __restrict__ srcs) {
    __shared__ int lhist[NPB];
    __shared__ int lcur[NPB];
    __shared__ int s_out[PB_CAP];
    int b = blockIdx.x;
    int node0 = b * NPB;
    int node1 = min(node0 + NPB, N_NODES);
    int nloc = node1 - node0;
    int beg = b * BCAP;
    int len = bcur[b] - beg;
    if (len > BCAP) len = BCAP;          // 35-sigma guard
    int t = threadIdx.x;
    const int SMASK = (1 << SRC_BITS) - 1;

    for (int i = t; i < NPB; i += PB_T) lhist[i] = 0;
    __syncthreads();
    for (int i = t; i < len; i += PB_T)
        atomicAdd(&lhist[packT[beg + i] >> SRC_BITS], 1);
    __syncthreads();
    if (t < 64) {   // exclusive scan of 391 counters: 7/lane + shfl
        int base = t * 7;
        int c[7]; int ssum = 0;
#pragma unroll
        for (int j = 0; j < 7; j++) {
            int idx = base + j;
            c[j] = (idx < NPB) ? lhist[idx] : 0;
            ssum += c[j];
        }
        int sc = ssum;
#pragma unroll
        for (int off = 1; off < 64; off <<= 1) {
            int v = __shfl_up(sc, off, 64);
            if (t >= off) sc += v;
        }
        int ex = sc - ssum;
#pragma unroll
        for (int j = 0; j < 7; j++) {
            int idx = base + j;
            if (idx < NPB) lcur[idx] = ex;
            ex += c[j];
        }
    }
    __syncthreads();
    // rowinfo from local exclusive prefix (before lcur mutates)
    for (int i = t; i < nloc; i += PB_T)
        rowinfo[node0 + i] = (lhist[i] << 22) | (beg + lcur[i]);
    __syncthreads();
    for (int i = t; i < len; i += PB_T) {
        int pk = packT[beg + i];
        int idx = atomicAdd(&lcur[pk >> SRC_BITS], 1);
        s_out[idx] = pk & SMASK;
    }
    __syncthreads();
    for (int i = t; i < len; i += PB_T)
        srcs[beg + i] = s_out[i];
}

// ---------------------------------------------------------------------------
// Layer-1 GEMM: hs16 = fp16( (x @ W1^T) * dinv ). KT=32 tiling + 1-deep
// register prefetch (measured 40.8 us steady, R11). Same FMA order ->
// bit-identical fp32 math.
// ---------------------------------------------------------------------------
#define GT   256
#define NTB  128     // nodes per block
#define KT2  32      // k-tile (4 passes for F_IN=128)
#define WS   68      // wT stride (floats)

__global__ __launch_bounds__(GT, 4) void k_gemm1(const float* __restrict__ x,
                                                 const float* __restrict__ W1,
                                                 const int* __restrict__ rowinfo,
                                                 __half* __restrict__ hs) {
    __shared__ float wT[KT2 * WS];      // 8.7 KB
    __shared__ float xT[KT2 * NTB];     // 16 KB
    int t = threadIdx.x;
    int node0 = blockIdx.x * NTB;
    int lane = t & 63, wv = t >> 6;
    int fi = lane & 15, ni = lane >> 4;
    int n0 = wv * 32 + ni * 8;
    // staging roles
    int fW = t & 63, kqW = t >> 6;       // wT: 8 k values (2 float4)
    int nX = t & 127, halfX = t >> 7;    // xT: 16 k values (4 float4)
    int nodeX = node0 + nX;
    bool xok = (nodeX < N_NODES);

    float4 wv_[2], xv_[4];
    {   // prologue: load pass-0 staging into registers
        const float4* wp = (const float4*)&W1[(size_t)fW * F_IN + kqW * 8];
        wv_[0] = wp[0]; wv_[1] = wp[1];
        if (xok) {
            const float4* xp = (const float4*)&x[(size_t)nodeX * F_IN + halfX * 16];
#pragma unroll
            for (int j = 0; j < 4; j++) xv_[j] = xp[j];
        } else {
#pragma unroll
            for (int j = 0; j < 4; j++) xv_[j] = make_float4(0.f, 0.f, 0.f, 0.f);
        }
    }

    float acc[4][8];
#pragma unroll
    for (int r = 0; r < 4; r++)
#pragma unroll
        for (int c = 0; c < 8; c++) acc[r][c] = 0.0f;

    for (int p = 0; p < 4; p++) {
        if (p) __syncthreads();          // prev compute done before LDS overwrite
        {   // write staged registers -> LDS
#pragma unroll
            for (int j = 0; j < 2; j++) {
                float4 v = wv_[j];
                int kl = kqW * 8 + 4 * j;
                wT[(kl + 0) * WS + fW] = v.x;
                wT[(kl + 1) * WS + fW] = v.y;
                wT[(kl + 2) * WS + fW] = v.z;
                wT[(kl + 3) * WS + fW] = v.w;
            }
#pragma unroll
            for (int j = 0; j < 4; j++) {
                float4 v = xv_[j];
                int kl = (halfX * 4 + j) * 4;
                xT[(kl + 0) * NTB + nX] = v.x;
                xT[(kl + 1) * NTB + nX] = v.y;
                xT[(kl + 2) * NTB + nX] = v.z;
                xT[(kl + 3) * NTB + nX] = v.w;
            }
        }
        __syncthreads();
        if (p < 3) {                     // prefetch next pass during compute
            int k0n = (p + 1) * KT2;
            const float4* wp = (const float4*)&W1[(size_t)fW * F_IN + k0n + kqW * 8];
            wv_[0] = wp[0]; wv_[1] = wp[1];
            if (xok) {
                const float4* xp = (const float4*)&x[(size_t)nodeX * F_IN + k0n + halfX * 16];
#pragma unroll
                for (int j = 0; j < 4; j++) xv_[j] = xp[j];
            }
        }
#pragma unroll 8
        for (int k = 0; k < KT2; k++) {
            float4 wf = *(const float4*)&wT[k * WS + fi * 4];
            float4 xa = *(const float4*)&xT[k * NTB + n0];
            float4 xb = *(const float4*)&xT[k * NTB + n0 + 4];
            float wr[4] = {wf.x, wf.y, wf.z, wf.w};
            float xv[8] = {xa.x, xa.y, xa.z, xa.w, xb.x, xb.y, xb.z, xb.w};
#pragma unroll
            for (int r = 0; r < 4; r++)
#pragma unroll
                for (int c = 0; c < 8; c++) acc[r][c] += wr[r] * xv[c];
        }
    }
#pragma unroll
    for (int c = 0; c < 8; c++) {
        int node = node0 + n0 + c;
        if (node < N_NODES) {
            float dv = rsqrtf((float)((rowinfo[node] >> 22) + 1));
            __half2 h0 = __floats2half2_rn(acc[0][c] * dv, acc[1][c] * dv);
            __half2 h1 = __floats2half2_rn(acc[2][c] * dv, acc[3][c] * dv);
            __half2* hp = (__half2*)&hs[(size_t)node * F_H + fi * 4];
            hp[0] = h0; hp[1] = h1;
        }
    }
}

// ---------------------------------------------------------------------------
// Aggregate L1 + relu + wc2 projection. Round-0 proven body, single dispatch.
// ---------------------------------------------------------------------------
__global__ void k_agg1q(const int* __restrict__ rowinfo, const int* __restrict__ srcs,
                        const __half* __restrict__ hs,
                        const float* __restrict__ b1, const float* __restrict__ wc2,
                        float* __restrict__ q) {
    unsigned tid = blockIdx.x * blockDim.x + threadIdx.x;
    unsigned node = tid >> 6;
    int lane = tid & 63;
    if (node >= N_NODES) return;
    int up = lane >> 5;            // 0 = even edges, 1 = odd edges
    int fp = lane & 31;            // feature pair: features 2fp, 2fp+1
    const __half2* hs2 = (const __half2*)hs;

    int ri = rowinfo[node];
    int beg = ri & 0x3FFFFF;
    int deg = ri >> 22;
    int end = beg + deg;
    float2 acc = make_float2(0.0f, 0.0f);
    if (up == 0) {                 // self-loop on lower half only
        float2 s = __half22float2(hs2[(size_t)node * 32 + fp]);
        acc.x = s.x; acc.y = s.y;
    }
    int j = beg;
    for (; j + 16 <= end; j += 16) {
        int s[16];
#pragma unroll
        for (int u = 0; u < 16; u++) s[u] = srcs[j + u];
#pragma unroll
        for (int u = 0; u < 8; u++) {
            int sel = up ? s[2 * u + 1] : s[2 * u];
            float2 v = __half22float2(hs2[(size_t)sel * 32 + fp]);
            acc.x += v.x; acc.y += v.y;
        }
    }
    for (; j + 2 <= end; j += 2) {
        int sel = up ? srcs[j + 1] : srcs[j];
        float2 v = __half22float2(hs2[(size_t)sel * 32 + fp]);
        acc.x += v.x; acc.y += v.y;
    }
    if (j < end && up == 0) {      // odd leftover edge: lower half only
        float2 v = __half22float2(hs2[(size_t)srcs[j] * 32 + fp]);
        acc.x += v.x; acc.y += v.y;
    }
    // combine halves (both halves then hold the full sum)
    acc.x += __shfl_xor(acc.x, 32, 64);
    acc.y += __shfl_xor(acc.y, 32, 64);
    // epilogue: z = relu(dinv*acc + b1); q = dinv * dot(z, wc2)
    float dv = rsqrtf((float)(deg + 1));
    float2 bb = *(const float2*)&b1[2 * fp];
    float2 ww = *(const float2*)&wc2[2 * fp];
    float z0 = fmaxf(fmaf(dv, acc.x, bb.x), 0.0f);
    float z1 = fmaxf(fmaf(dv, acc.y, bb.y), 0.0f);
    float p = z0 * ww.x + z1 * ww.y;
#pragma unroll
    for (int off = 16; off > 0; off >>= 1)
        p += __shfl_xor(p, off, 64);
    if (lane == 0) q[node] = dv * p;
}

// ---------------------------------------------------------------------------
// Final: out[d] = dinv[d] * (q[d] + sum_{s->d} q[s]) + c0
// 8 lanes per node, coalesced 32B srcs reads per group, 3-step shfl reduce.
// ---------------------------------------------------------------------------
#define KF_T 256
__global__ __launch_bounds__(KF_T) void k_final(const int* __restrict__ rowinfo,
                                                const int* __restrict__ srcs,
                                                const float* __restrict__ q,
                                                const float* __restrict__ c0,
                                                float* __restrict__ out) {
    int t = blockIdx.x * KF_T + threadIdx.x;
    int node = t >> 3;
    int sl = t & 7;
    if (node >= N_NODES) return;
    int ri = rowinfo[node];
    int beg = ri & 0x3FFFFF;
    int deg = ri >> 22;
    float acc = 0.0f;
    for (int j = beg + sl; j < beg + deg; j += 8)
        acc += q[srcs[j]];
    acc += __shfl_xor(acc, 1, 64);
    acc += __shfl_xor(acc, 2, 64);
    acc += __shfl_xor(acc, 4, 64);
    if (sl == 0)
        out[node] = rsqrtf((float)(deg + 1)) * (q[node] + acc) + c0[0];
}

// ---------------------------------------------------------------------------
extern "C" void kernel_launch(void* const* d_in, const int* in_sizes, int n_in,
                              void* d_out, int out_size, void* d_ws, size_t ws_size,
                              hipStream_t stream) {
    const float* x  = (const float*)d_in[0];
    const int*   ei = (const int*)d_in[1];
    const int*   src = ei;
    const int*   dst = ei + N_EDGES;
    const float* W1 = (const float*)d_in[2];
    const float* b1 = (const float*)d_in[3];
    const float* W2 = (const float*)d_in[4];
    const float* b2 = (const float*)d_in[5];
    const float* Wc = (const float*)d_in[6];
    const float* bc = (const float*)d_in[7];
    float* out = (float*)d_out;

    char* w = (char*)d_ws;
    int*    bcur    = (int*)w;    w += NBUCK * 4;
    float*  wc2     = (float*)w;  w += 64 * 4;
    float*  c0      = (float*)w;  w += 4 * 4;
    int*    rowinfo = (int*)w;    w += (size_t)N_NODES * 4;
    float*  q       = (float*)w;  w += (size_t)N_NODES * 4;
    int*    srcs    = (int*)w;    w += (size_t)NBUCK * BCAP * 4;    // 16.8 MB
    // packT dead after k_partB; bufA (hs) written by k_gemm1 afterwards -> alias
    char*   shared_region = w;
    int*    packT   = (int*)shared_region;     // NBUCK*BCAP*4 = 16.8 MB
    __half* bufA    = (__half*)shared_region;  // N_NODES*128 B = 12.8 MB
    w += (size_t)NBUCK * BCAP * 4 + 256;

    const int TB = 256;
    const int NB_PA = (int)(((long long)N_EDGES + PA_C - 1) / PA_C);  // 782
    const int NB_G  = (N_NODES + NTB - 1) / NTB;                      // 782
    const int NB_AG = ((unsigned)N_NODES * 64 + TB - 1) / TB;         // 25000
    const int NB_KF = (N_NODES * 8 + KF_T - 1) / KF_T;                // 3125

    k_init <<<1, 256, 0, stream>>>(W2, Wc, b2, bc, wc2, c0, bcur);
    k_partA<<<NB_PA, PA_T, 0, stream>>>(src, dst, bcur, packT);
    k_partB<<<NBUCK, PB_T, 0, stream>>>(bcur, packT, rowinfo, srcs);

    // layer 1: gemm (KT=32 + register prefetch) -> hs fp16 (overwrites packT)
    k_gemm1<<<NB_G, GT, 0, stream>>>(x, W1, rowinfo, bufA);

    // aggregate+relu+project -> q (single dispatch)
    k_agg1q<<<NB_AG, TB, 0, stream>>>(rowinfo, srcs, bufA, b1, wc2, q);

    // collapsed layer 2 + head: 8-lane-per-node gather over q
    k_final<<<NB_KF, KF_T, 0, stream>>>(rowinfo, srcs, q, c0, out);
}

// Round 13
// 279.684 us; speedup vs baseline: 1.0778x; 1.0082x over previous
//
#include <hip/hip_runtime.h>
#include <hip/hip_bf16.h>
#include <hip/hip_fp16.h>

#define N_NODES 100000
#define N_EDGES 3200000
#define F_IN    128
#define F_H     64

#define NBUCK 256
#define NPB   391            // ceil(N_NODES / NBUCK); last bucket short
#define SRC_BITS 17          // N_NODES < 2^17; pack = (dstLocal<<17)|src
#define BCAP  16384          // fixed per-bucket capacity (mean 12.5K, 35 sigma)

// ---------------------------------------------------------------------------
// Init: bucket cursors to fixed bases; wc2 = W2^T Wc; c0 = Wc.b2 + bc
// ---------------------------------------------------------------------------
__global__ __launch_bounds__(256) void k_init(const float* __restrict__ W2,
                                              const float* __restrict__ Wc,
                                              const float* __restrict__ b2,
                                              const float* __restrict__ bc,
                                              float* __restrict__ wc2,
                                              float* __restrict__ c0,
                                              int* __restrict__ bcur) {
    int t = threadIdx.x;
    bcur[t] = t * BCAP;
    if (t < 64) {
        float s = 0.0f;
#pragma unroll 8
        for (int f = 0; f < F_H; f++) s += Wc[f] * W2[f * F_H + t];
        wc2[t] = s;
        float p = Wc[t] * b2[t];
#pragma unroll
        for (int off = 32; off > 0; off >>= 1) p += __shfl_xor(p, off, 64);
        if (t == 0) c0[0] = p + bc[0];
    }
}

// ---------------------------------------------------------------------------
// Pass A: partition edges into NBUCK fixed-capacity dst-range buckets; emit
// packed (dstLocal<<17)|src words (LDS-staged, coalesced out)
// ---------------------------------------------------------------------------
#define PA_T   256
#define PA_C   4096
#define PA_PER (PA_C / PA_T)   // 16
__global__ __launch_bounds__(PA_T) void k_partA(const int* __restrict__ src,
                                                const int* __restrict__ dst,
                                                int* __restrict__ bucket_cursor,
                                                int* __restrict__ packT) {
    __shared__ int lcount[NBUCK];
    __shared__ int lstart[NBUCK];
    __shared__ int loffs[NBUCK];
    __shared__ int lbase[NBUCK];
    __shared__ int s_pack[PA_C];
    __shared__ unsigned char s_bkt[PA_C];
    __shared__ int ltot;
    int t = threadIdx.x;
    long long e0 = (long long)blockIdx.x * PA_C;
    if (t < NBUCK) lcount[t] = 0;
    __syncthreads();
    int ep[PA_PER];
    short eb[PA_PER];
#pragma unroll
    for (int i = 0; i < PA_PER; i++) {
        long long e = e0 + i * PA_T + t;
        if (e < N_EDGES) {
            int es = src[e], ed = dst[e];
            int b = ed / NPB;
            eb[i] = (short)b;
            ep[i] = ((ed - b * NPB) << SRC_BITS) | es;
            atomicAdd(&lcount[b], 1);
        } else eb[i] = -1;
    }
    __syncthreads();
    // exclusive scan of lcount (256) by wave 0: 4 serial/lane + shfl scan
    if (t < 64) {
        int base = t * 4;
        int c0 = lcount[base], c1 = lcount[base + 1], c2 = lcount[base + 2], c3 = lcount[base + 3];
        int ssum = c0 + c1 + c2 + c3;
        int sc = ssum;
#pragma unroll
        for (int off = 1; off < 64; off <<= 1) {
            int v = __shfl_up(sc, off, 64);
            if (t >= off) sc += v;
        }
        int ex = sc - ssum;
        lstart[base]     = ex;
        lstart[base + 1] = ex + c0;
        lstart[base + 2] = ex + c0 + c1;
        lstart[base + 3] = ex + c0 + c1 + c2;
        if (t == 63) ltot = sc;
    }
    __syncthreads();
    if (t < NBUCK) {
        loffs[t] = lstart[t];
        int c = lcount[t];
        lbase[t] = c ? atomicAdd(&bucket_cursor[t], c) : 0;
    }
    __syncthreads();
#pragma unroll
    for (int i = 0; i < PA_PER; i++) {
        if (eb[i] >= 0) {
            int idx = atomicAdd(&loffs[eb[i]], 1);
            s_pack[idx] = ep[i];
            s_bkt[idx] = (unsigned char)eb[i];
        }
    }
    __syncthreads();
    int tot = ltot;
    for (int i = t; i < tot; i += PA_T) {
        int b = s_bkt[i];
        int addr = lbase[b] + (i - lstart[b]);
        packT[addr] = s_pack[i];
    }
}

// ---------------------------------------------------------------------------
// Pass B: R6-proven full counting sort. Histogram pass + scan + LDS s_out
// scatter + coalesced copy-out. Emits rowinfo=(deg<<22)|start.
// ---------------------------------------------------------------------------
#define PB_T   1024
#define PB_CAP 16384
__global__ __launch_bounds__(PB_T) void k_partB(const int* __restrict__ bcur,
                                                const int* __restrict__ packT,
                                                int* __restrict__ rowinfo,
                                                int* __restrict__ srcs) {
    __shared__ int lhist[NPB];
    __shared__ int lcur[NPB];
    __shared__ int s_out[PB_CAP];
    int b = blockIdx.x;
    int node0 = b * NPB;
    int node1 = min(node0 + NPB, N_NODES);
    int nloc = node1 - node0;
    int beg = b * BCAP;
    int len = bcur[b] - beg;
    if (len > BCAP) len = BCAP;          // 35-sigma guard
    int t = threadIdx.x;
    const int SMASK = (1 << SRC_BITS) - 1;

    for (int i = t; i < NPB; i += PB_T) lhist[i] = 0;
    __syncthreads();
    for (int i = t; i < len; i += PB_T)
        atomicAdd(&lhist[packT[beg + i] >> SRC_BITS], 1);
    __syncthreads();
    if (t < 64) {   // exclusive scan of 391 counters: 7/lane + shfl
        int base = t * 7;
        int c[7]; int ssum = 0;
#pragma unroll
        for (int j = 0; j < 7; j++) {
            int idx = base + j;
            c[j] = (idx < NPB) ? lhist[idx] : 0;
            ssum += c[j];
        }
        int sc = ssum;
#pragma unroll
        for (int off = 1; off < 64; off <<= 1) {
            int v = __shfl_up(sc, off, 64);
            if (t >= off) sc += v;
        }
        int ex = sc - ssum;
#pragma unroll
        for (int j = 0; j < 7; j++) {
            int idx = base + j;
            if (idx < NPB) lcur[idx] = ex;
            ex += c[j];
        }
    }
    __syncthreads();
    // rowinfo from local exclusive prefix (before lcur mutates)
    for (int i = t; i < nloc; i += PB_T)
        rowinfo[node0 + i] = (lhist[i] << 22) | (beg + lcur[i]);
    __syncthreads();
    for (int i = t; i < len; i += PB_T) {
        int pk = packT[beg + i];
        int idx = atomicAdd(&lcur[pk >> SRC_BITS], 1);
        s_out[idx] = pk & SMASK;
    }
    __syncthreads();
    for (int i = t; i < len; i += PB_T)
        srcs[beg + i] = s_out[i];
}

// ---------------------------------------------------------------------------
// Layer-1 GEMM: hs16 = fp16( (x @ W1^T) * dinv ).
// R13 re-tile for TLP: NTB=64 nodes/block, 4 waves (wave owns 16 nodes),
// per-lane 4-feat x 4-node acc. LDS 17.1 KB, VGPR ~56 -> 8 blocks/CU cap,
// grid 1563 -> ~6 blocks/CU, ~24 waves/CU resident (4x the old NTB=128
// config whose occupancy was 19%). Register prefetch retained. Same
// k-ascending accumulation per (feature,node) -> bit-identical fp32 math.
// ---------------------------------------------------------------------------
#define GT   256
#define NTB  64      // nodes per block
#define KT2  32      // k-tile (4 passes for F_IN=128)
#define WS   68      // wT row stride (floats)
#define XS   66      // xT row stride (floats)

__global__ __launch_bounds__(GT, 8) void k_gemm1(const float* __restrict__ x,
                                                 const float* __restrict__ W1,
                                                 const int* __restrict__ rowinfo,
                                                 __half* __restrict__ hs) {
    __shared__ float wT[KT2 * WS];      // 8.7 KB
    __shared__ float xT[KT2 * XS];      // 8.4 KB (XS >= NTB+pad)
    int t = threadIdx.x;
    int node0 = blockIdx.x * NTB;
    int lane = t & 63, wv = t >> 6;
    int fi = lane & 15;                 // features 4fi..4fi+3
    int ni = lane >> 4;                 // node subgroup 0..3
    int nb = wv * 16 + ni * 4;          // node offset within block
    // staging roles: both tables use (t&63, t>>6)
    int fW = t & 63, kq = t >> 6;       // 8 k values each (2 float4)
    int nX = t & 63;
    int nodeX = node0 + nX;
    bool xok = (nodeX < N_NODES);

    float4 wv_[2], xv_[2];
    {   // prologue: load pass-0 staging into registers
        const float4* wp = (const float4*)&W1[(size_t)fW * F_IN + kq * 8];
        wv_[0] = wp[0]; wv_[1] = wp[1];
        if (xok) {
            const float4* xp = (const float4*)&x[(size_t)nodeX * F_IN + kq * 8];
            xv_[0] = xp[0]; xv_[1] = xp[1];
        } else {
            xv_[0] = make_float4(0.f, 0.f, 0.f, 0.f);
            xv_[1] = make_float4(0.f, 0.f, 0.f, 0.f);
        }
    }

    float acc[4][4];                    // [feature r][node c]
#pragma unroll
    for (int r = 0; r < 4; r++)
#pragma unroll
        for (int c = 0; c < 4; c++) acc[r][c] = 0.0f;

    for (int p = 0; p < 4; p++) {
        if (p) __syncthreads();          // prev compute done before LDS overwrite
        {   // write staged registers -> LDS
#pragma unroll
            for (int j = 0; j < 2; j++) {
                float4 v = wv_[j];
                int kl = kq * 8 + 4 * j;
                wT[(kl + 0) * WS + fW] = v.x;
                wT[(kl + 1) * WS + fW] = v.y;
                wT[(kl + 2) * WS + fW] = v.z;
                wT[(kl + 3) * WS + fW] = v.w;
            }
#pragma unroll
            for (int j = 0; j < 2; j++) {
                float4 v = xv_[j];
                int kl = kq * 8 + 4 * j;
                xT[(kl + 0) * XS + nX] = v.x;
                xT[(kl + 1) * XS + nX] = v.y;
                xT[(kl + 2) * XS + nX] = v.z;
                xT[(kl + 3) * XS + nX] = v.w;
            }
        }
        __syncthreads();
        if (p < 3) {                     // prefetch next pass during compute
            int k0n = (p + 1) * KT2;
            const float4* wp = (const float4*)&W1[(size_t)fW * F_IN + k0n + kq * 8];
            wv_[0] = wp[0]; wv_[1] = wp[1];
            if (xok) {
                const float4* xp = (const float4*)&x[(size_t)nodeX * F_IN + k0n + kq * 8];
                xv_[0] = xp[0]; xv_[1] = xp[1];
            }
        }
#pragma unroll 8
        for (int k = 0; k < KT2; k++) {
            float4 wf = *(const float4*)&wT[k * WS + fi * 4];
            float4 xa = *(const float4*)&xT[k * XS + nb];
            float wr[4] = {wf.x, wf.y, wf.z, wf.w};
            float xv[4] = {xa.x, xa.y, xa.z, xa.w};
#pragma unroll
            for (int r = 0; r < 4; r++)
#pragma unroll
                for (int c = 0; c < 4; c++) acc[r][c] += wr[r] * xv[c];
        }
    }
#pragma unroll
    for (int c = 0; c < 4; c++) {
        int node = node0 + nb + c;
        if (node < N_NODES) {
            float dv = rsqrtf((float)((rowinfo[node] >> 22) + 1));
            __half2 h0 = __floats2half2_rn(acc[0][c] * dv, acc[1][c] * dv);
            __half2 h1 = __floats2half2_rn(acc[2][c] * dv, acc[3][c] * dv);
            __half2* hp = (__half2*)&hs[(size_t)node * F_H + fi * 4];
            hp[0] = h0; hp[1] = h1;
        }
    }
}

// ---------------------------------------------------------------------------
// Aggregate L1 + relu + wc2 projection. Round-0 proven body, single dispatch.
// ---------------------------------------------------------------------------
__global__ void k_agg1q(const int* __restrict__ rowinfo, const int* __restrict__ srcs,
                        const __half* __restrict__ hs,
                        const float* __restrict__ b1, const float* __restrict__ wc2,
                        float* __restrict__ q) {
    unsigned tid = blockIdx.x * blockDim.x + threadIdx.x;
    unsigned node = tid >> 6;
    int lane = tid & 63;
    if (node >= N_NODES) return;
    int up = lane >> 5;            // 0 = even edges, 1 = odd edges
    int fp = lane & 31;            // feature pair: features 2fp, 2fp+1
    const __half2* hs2 = (const __half2*)hs;

    int ri = rowinfo[node];
    int beg = ri & 0x3FFFFF;
    int deg = ri >> 22;
    int end = beg + deg;
    float2 acc = make_float2(0.0f, 0.0f);
    if (up == 0) {                 // self-loop on lower half only
        float2 s = __half22float2(hs2[(size_t)node * 32 + fp]);
        acc.x = s.x; acc.y = s.y;
    }
    int j = beg;
    for (; j + 16 <= end; j += 16) {
        int s[16];
#pragma unroll
        for (int u = 0; u < 16; u++) s[u] = srcs[j + u];
#pragma unroll
        for (int u = 0; u < 8; u++) {
            int sel = up ? s[2 * u + 1] : s[2 * u];
            float2 v = __half22float2(hs2[(size_t)sel * 32 + fp]);
            acc.x += v.x; acc.y += v.y;
        }
    }
    for (; j + 2 <= end; j += 2) {
        int sel = up ? srcs[j + 1] : srcs[j];
        float2 v = __half22float2(hs2[(size_t)sel * 32 + fp]);
        acc.x += v.x; acc.y += v.y;
    }
    if (j < end && up == 0) {      // odd leftover edge: lower half only
        float2 v = __half22float2(hs2[(size_t)srcs[j] * 32 + fp]);
        acc.x += v.x; acc.y += v.y;
    }
    // combine halves (both halves then hold the full sum)
    acc.x += __shfl_xor(acc.x, 32, 64);
    acc.y += __shfl_xor(acc.y, 32, 64);
    // epilogue: z = relu(dinv*acc + b1); q = dinv * dot(z, wc2)
    float dv = rsqrtf((float)(deg + 1));
    float2 bb = *(const float2*)&b1[2 * fp];
    float2 ww = *(const float2*)&wc2[2 * fp];
    float z0 = fmaxf(fmaf(dv, acc.x, bb.x), 0.0f);
    float z1 = fmaxf(fmaf(dv, acc.y, bb.y), 0.0f);
    float p = z0 * ww.x + z1 * ww.y;
#pragma unroll
    for (int off = 16; off > 0; off >>= 1)
        p += __shfl_xor(p, off, 64);
    if (lane == 0) q[node] = dv * p;
}

// ---------------------------------------------------------------------------
// Final: out[d] = dinv[d] * (q[d] + sum_{s->d} q[s]) + c0
// 8 lanes per node, coalesced 32B srcs reads per group, 3-step shfl reduce.
// ---------------------------------------------------------------------------
#define KF_T 256
__global__ __launch_bounds__(KF_T) void k_final(const int* __restrict__ rowinfo,
                                                const int* __restrict__ srcs,
                                                const float* __restrict__ q,
                                                const float* __restrict__ c0,
                                                float* __restrict__ out) {
    int t = blockIdx.x * KF_T + threadIdx.x;
    int node = t >> 3;
    int sl = t & 7;
    if (node >= N_NODES) return;
    int ri = rowinfo[node];
    int beg = ri & 0x3FFFFF;
    int deg = ri >> 22;
    float acc = 0.0f;
    for (int j = beg + sl; j < beg + deg; j += 8)
        acc += q[srcs[j]];
    acc += __shfl_xor(acc, 1, 64);
    acc += __shfl_xor(acc, 2, 64);
    acc += __shfl_xor(acc, 4, 64);
    if (sl == 0)
        out[node] = rsqrtf((float)(deg + 1)) * (q[node] + acc) + c0[0];
}

// ---------------------------------------------------------------------------
extern "C" void kernel_launch(void* const* d_in, const int* in_sizes, int n_in,
                              void* d_out, int out_size, void* d_ws, size_t ws_size,
                              hipStream_t stream) {
    const float* x  = (const float*)d_in[0];
    const int*   ei = (const int*)d_in[1];
    const int*   src = ei;
    const int*   dst = ei + N_EDGES;
    const float* W1 = (const float*)d_in[2];
    const float* b1 = (const float*)d_in[3];
    const float* W2 = (const float*)d_in[4];
    const float* b2 = (const float*)d_in[5];
    const float* Wc = (const float*)d_in[6];
    const float* bc = (const float*)d_in[7];
    float* out = (float*)d_out;

    char* w = (char*)d_ws;
    int*    bcur    = (int*)w;    w += NBUCK * 4;
    float*  wc2     = (float*)w;  w += 64 * 4;
    float*  c0      = (float*)w;  w += 4 * 4;
    int*    rowinfo = (int*)w;    w += (size_t)N_NODES * 4;
    float*  q       = (float*)w;  w += (size_t)N_NODES * 4;
    int*    srcs    = (int*)w;    w += (size_t)NBUCK * BCAP * 4;    // 16.8 MB
    // packT dead after k_partB; bufA (hs) written by k_gemm1 afterwards -> alias
    char*   shared_region = w;
    int*    packT   = (int*)shared_region;     // NBUCK*BCAP*4 = 16.8 MB
    __half* bufA    = (__half*)shared_region;  // N_NODES*128 B = 12.8 MB
    w += (size_t)NBUCK * BCAP * 4 + 256;

    const int TB = 256;
    const int NB_PA = (int)(((long long)N_EDGES + PA_C - 1) / PA_C);  // 782
    const int NB_G  = (N_NODES + NTB - 1) / NTB;                      // 1563
    const int NB_AG = ((unsigned)N_NODES * 64 + TB - 1) / TB;         // 25000
    const int NB_KF = (N_NODES * 8 + KF_T - 1) / KF_T;                // 3125

    k_init <<<1, 256, 0, stream>>>(W2, Wc, b2, bc, wc2, c0, bcur);
    k_partA<<<NB_PA, PA_T, 0, stream>>>(src, dst, bcur, packT);
    k_partB<<<NBUCK, PB_T, 0, stream>>>(bcur, packT, rowinfo, srcs);

    // layer 1: gemm (NTB=64 TLP re-tile) -> hs fp16 (overwrites packT)
    k_gemm1<<<NB_G, GT, 0, stream>>>(x, W1, rowinfo, bufA);

    // aggregate+relu+project -> q (single dispatch)
    k_agg1q<<<NB_AG, TB, 0, stream>>>(rowinfo, srcs, bufA, b1, wc2, q);

    // collapsed layer 2 + head: 8-lane-per-node gather over q
    k_final<<<NB_KF, KF_T, 0, stream>>>(rowinfo, srcs, q, c0, out);
}